// Round 6
// baseline (258.366 us; speedup 1.0000x reference)
//
#include <hip/hip_runtime.h>
#include <hip/hip_bf16.h>
#include <math.h>

#define T_SEQ 4096
#define C_EMB 768
#define NHEAD 12
#define HDIM  64

typedef __bf16 bf16;
typedef __bf16 bf16x8 __attribute__((ext_vector_type(8)));
typedef __bf16 bf16x4 __attribute__((ext_vector_type(4)));
typedef float  f32x4  __attribute__((ext_vector_type(4)));

// ---------------------------------------------------------------- utilities

__device__ __forceinline__ void stage16(const void* g, void* ldsbase) {
  // global -> LDS direct, 16B per lane; LDS dest = wave-uniform base + lane*16
  __builtin_amdgcn_global_load_lds(
      (__attribute__((address_space(1))) const unsigned int*)g,
      (__attribute__((address_space(3))) unsigned int*)ldsbase, 16, 0, 0);
}

// -------------------------------------------------- weight convert+transpose
// W [K][N] f32  ->  Wt [N][K] bf16
__global__ void wt_transpose(const float* __restrict__ W, bf16* __restrict__ Wt,
                             int K, int N) {
  __shared__ float tile[32][33];
  const int n0 = blockIdx.x * 32, k0 = blockIdx.y * 32;
  const int tx = threadIdx.x & 31, ty = threadIdx.x >> 5;  // 256 thr: ty 0..7
#pragma unroll
  for (int i = 0; i < 32; i += 8)
    tile[ty + i][tx] = W[(size_t)(k0 + ty + i) * N + n0 + tx];
  __syncthreads();
#pragma unroll
  for (int i = 0; i < 32; i += 8)
    Wt[(size_t)(n0 + ty + i) * K + k0 + tx] = (bf16)tile[tx][ty + i];
}

// ------------------------------------------------------------------ layernorm
// x [4096][768] f32 -> y bf16
__global__ void ln_rows(const float* __restrict__ x, bf16* __restrict__ y) {
  const int row = blockIdx.x;
  const float* xr = x + (size_t)row * C_EMB;
  const int t = threadIdx.x;  // 256
  float v0 = xr[t], v1 = xr[t + 256], v2 = xr[t + 512];
  float s  = v0 + v1 + v2;
  float ss = v0 * v0 + v1 * v1 + v2 * v2;
#pragma unroll
  for (int m = 1; m < 64; m <<= 1) {
    s += __shfl_xor(s, m);
    ss += __shfl_xor(ss, m);
  }
  __shared__ float bs[4], bq[4];
  const int w = t >> 6;
  if ((t & 63) == 0) { bs[w] = s; bq[w] = ss; }
  __syncthreads();
  s  = bs[0] + bs[1] + bs[2] + bs[3];
  ss = bq[0] + bq[1] + bq[2] + bq[3];
  const float mu  = s * (1.0f / C_EMB);
  const float var = ss * (1.0f / C_EMB) - mu * mu;
  const float rs  = rsqrtf(var + 1e-5f);
  bf16* yr = y + (size_t)row * C_EMB;
  yr[t]       = (bf16)((v0 - mu) * rs);
  yr[t + 256] = (bf16)((v1 - mu) * rs);
  yr[t + 512] = (bf16)((v2 - mu) * rs);
}

// ------------------------------------------------------------------ GEMM
// C[M][N] = A[M][K](bf16 rowmajor) x BT[N][K](bf16)   (i.e. A @ B)
// Simple single-buffer m97 pattern. Measured best (R2/R3): explicit
// dbuf/pipelining REGRESSED (R4/R5) -- implicit multi-block overlap already
// hides staging latency at 3-4 blocks/CU (guide Common-mistake #5).
// EPI 0: store bf16        EPI 1: f32 = res + acc
// EPI 2: bf16 = gelu(acc + bias[c])   EPI 3: f32 = res + acc
template <int EPI>
__global__ void gemm_bt(const bf16* __restrict__ A, const bf16* __restrict__ BT,
                        void* __restrict__ Cout, const float* __restrict__ res,
                        const float* __restrict__ bias, int M, int N, int K) {
  __shared__ __align__(16) bf16 As[128 * 32];
  __shared__ __align__(16) bf16 Bs[128 * 32];
  const int row0 = blockIdx.x * 128, col0 = blockIdx.y * 128;
  const int tid = threadIdx.x;
  const int w = tid >> 6, lane = tid & 63;
  const int wr = w >> 1, wc = w & 1;
  const int l15 = lane & 15, l4 = lane >> 4;

  f32x4 acc[4][4];
#pragma unroll
  for (int m = 0; m < 4; m++)
#pragma unroll
    for (int n = 0; n < 4; n++) acc[m][n] = (f32x4){0.f, 0.f, 0.f, 0.f};

  const int rr = lane >> 2;        // 16 rows per 1KB wave-instr
  const int c8 = (lane & 3) * 8;   // 4 chunks of 8 bf16 per 64B row

  for (int k0 = 0; k0 < K; k0 += 32) {
    const bf16* gA = A + (size_t)(row0 + w * 32 + rr) * K + k0 + c8;
    const bf16* gB = BT + (size_t)(col0 + w * 32 + rr) * K + k0 + c8;
    stage16(gA, As + (w * 32) * 32);
    stage16(gA + (size_t)16 * K, As + (w * 32 + 16) * 32);
    stage16(gB, Bs + (w * 32) * 32);
    stage16(gB + (size_t)16 * K, Bs + (w * 32 + 16) * 32);
    __syncthreads();

    bf16x8 af[4], bfv[4];
#pragma unroll
    for (int m = 0; m < 4; m++)
      af[m] = *reinterpret_cast<const bf16x8*>(As + (wr * 64 + m * 16 + l15) * 32 + l4 * 8);
#pragma unroll
    for (int n = 0; n < 4; n++)
      bfv[n] = *reinterpret_cast<const bf16x8*>(Bs + (wc * 64 + n * 16 + l15) * 32 + l4 * 8);
#pragma unroll
    for (int m = 0; m < 4; m++)
#pragma unroll
      for (int n = 0; n < 4; n++)
        acc[m][n] = __builtin_amdgcn_mfma_f32_16x16x32_bf16(af[m], bfv[n], acc[m][n], 0, 0, 0);
    __syncthreads();
  }

  const int orow = row0 + wr * 64;
  const int ocol = col0 + wc * 64;
#pragma unroll
  for (int m = 0; m < 4; m++) {
#pragma unroll
    for (int n = 0; n < 4; n++) {
      const int c = ocol + n * 16 + l15;
#pragma unroll
      for (int j = 0; j < 4; j++) {
        const int r = orow + m * 16 + l4 * 4 + j;  // C/D: col=lane&15, row=(lane>>4)*4+reg
        const size_t idx = (size_t)r * N + c;
        const float v = acc[m][n][j];
        if (EPI == 0) {
          ((bf16*)Cout)[idx] = (bf16)v;
        } else if (EPI == 1) {
          ((float*)Cout)[idx] = res[idx] + v;
        } else if (EPI == 2) {
          const float h = v + bias[c];
          ((bf16*)Cout)[idx] = (bf16)(0.5f * h * (1.0f + erff(h * 0.70710678118f)));
        } else {
          ((float*)Cout)[idx] = res[idx] + v;
        }
      }
    }
  }
}

// ------------------------------------------------------------------ attention
// kqv [T][2304] bf16 : k at +0, q at +768, v at +1536, head offset h*64
// out [T][768] bf16
//
// Block = 2 waves x 32 q-rows (QB=64), 128 threads; KV tile = 128 keys.
// Each wave owns TWO 16-q groups (A: +l15, B: +16+l15) so every K/V LDS
// fragment read feeds two MFMAs -> per-block-iter LDS traffic drops
// 160KB -> 96KB (this kernel is LDS-BW bound).
//
// Swapped QK^T (S^T = mfma(K,Q)); Q pre-scaled by 0.125*log2e; NO-MAX
// softmax (|st| <~ 30 << 127 so exp2 can't overflow; O/L == softmax exactly).
// lrun via MFMA ones-trick. Key-relabel: position p = 32kc+16hi+4g+r gets
// label l = 32kc+8g+4hi+r (bijective), pairing tiles 2kc,2kc+1 so the PV
// B-frag is lane-local: pb[j] = st[2kc + (j>>2)][j&3]. V is scattered to
// Vt[d][label] during staging. K/V reg-staged with cross-iter prefetch.
__global__ __launch_bounds__(128, 2)
void attn_fused(const bf16* __restrict__ kqv, bf16* __restrict__ out) {
  const int qb = blockIdx.x, h = blockIdx.y;
  const int tid = threadIdx.x, w = tid >> 6, lane = tid & 63;
  const int l15 = lane & 15, l4 = lane >> 4;

  __shared__ __align__(16) bf16 Ks[128 * 64];   // [pos][d], chunk ^ (pos&7)
  __shared__ __align__(16) bf16 Vt[64 * 128];   // [d][label], chunk ^ (d&7)
  char* const KsB = (char*)Ks;
  char* const VtB = (char*)Vt;

  // Q fragments (B operand), pre-scaled by scale*log2(e)
  const int qbase = qb * 64 + w * 32;
  const bf16* qpA = kqv + (size_t)(qbase + l15) * 2304 + 768 + h * 64 + l4 * 8;
  const bf16* qpB = qpA + (size_t)16 * 2304;
  bf16x8 qfA0 = *reinterpret_cast<const bf16x8*>(qpA);
  bf16x8 qfA1 = *reinterpret_cast<const bf16x8*>(qpA + 32);
  bf16x8 qfB0 = *reinterpret_cast<const bf16x8*>(qpB);
  bf16x8 qfB1 = *reinterpret_cast<const bf16x8*>(qpB + 32);
  const float cscale = 0.125f * 1.4426950408889634f;
#pragma unroll
  for (int e = 0; e < 8; e++) {
    qfA0[e] = (bf16)((float)qfA0[e] * cscale);
    qfA1[e] = (bf16)((float)qfA1[e] * cscale);
    qfB0[e] = (bf16)((float)qfB0[e] * cscale);
    qfB1[e] = (bf16)((float)qfB1[e] * cscale);
  }
  bf16x8 ones;
#pragma unroll
  for (int e = 0; e < 8; e++) ones[e] = (bf16)1.0f;

  f32x4 accLA = (f32x4){0.f, 0.f, 0.f, 0.f};
  f32x4 accLB = (f32x4){0.f, 0.f, 0.f, 0.f};
  f32x4 accOA[4], accOB[4];
#pragma unroll
  for (int dt = 0; dt < 4; dt++) {
    accOA[dt] = (f32x4){0.f, 0.f, 0.f, 0.f};
    accOB[dt] = (f32x4){0.f, 0.f, 0.f, 0.f};
  }

  // K staging: thread owns full row krow (128B = 8 chunks)
  const int krow = tid;
  const int swK = krow & 7;
  // V staging: thread owns keys kb*4..+3, d = db*16..+15
  const int kb = tid & 31, db = tid >> 5;
  // label base for key m = kb*4: l = 32*(m>>5) + 8*((m>>2)&3) + 4*((m>>4)&1)
  const int lb = ((kb & 0x18) << 2) | ((kb & 3) << 3) | (kb & 4);
  const int lchunk = lb >> 3, lbyte = (lb & 7) * 2;

  bf16x8 kreg[8];
  bf16x8 vreg[4][2];
#define LOADKV(kt)                                                               \
  {                                                                              \
    const bf16* kp = kqv + (size_t)((kt)*128 + krow) * 2304 + h * 64;            \
    _Pragma("unroll") for (int c = 0; c < 8; c++)                                \
        kreg[c] = *reinterpret_cast<const bf16x8*>(kp + c * 8);                  \
    const bf16* vp =                                                             \
        kqv + (size_t)((kt)*128 + kb * 4) * 2304 + 1536 + h * 64 + db * 16;      \
    _Pragma("unroll") for (int r = 0; r < 4; r++) {                              \
      vreg[r][0] = *reinterpret_cast<const bf16x8*>(vp + (size_t)r * 2304);      \
      vreg[r][1] = *reinterpret_cast<const bf16x8*>(vp + (size_t)r * 2304 + 8);  \
    }                                                                            \
  }

  LOADKV(0);
  const int sw = (l15 & 7) << 4;

  for (int kt = 0; kt < 32; kt++) {
    __syncthreads();
    // ---- LDS writes from registers (no global latency inside barriers)
    {
      char* kdst = KsB + krow * 128;
#pragma unroll
      for (int c = 0; c < 8; c++)
        *reinterpret_cast<bf16x8*>(kdst + ((c ^ swK) << 4)) = kreg[c];
#pragma unroll
      for (int hh = 0; hh < 2; hh++)
#pragma unroll
        for (int e = 0; e < 8; e++) {
          const int d = db * 16 + hh * 8 + e;
          const bf16x4 pk4 = (bf16x4){vreg[0][hh][e], vreg[1][hh][e],
                                      vreg[2][hh][e], vreg[3][hh][e]};
          *reinterpret_cast<bf16x4*>(VtB + d * 256 + ((lchunk ^ (d & 7)) << 4) + lbyte) = pk4;
        }
    }
    __syncthreads();
    if (kt + 1 < 32) LOADKV(kt + 1);  // prefetch flies during compute

    // ---- 4 sub-rounds: QK (tiles 2kc,2kc+1) -> exp2 -> PV chunk kc
#pragma unroll
    for (int kc = 0; kc < 4; kc++) {
      f32x4 sA[2], sB[2];
#pragma unroll
      for (int hi = 0; hi < 2; hi++) {
        const char* kr = KsB + (16 * (2 * kc + hi) + l15) * 128;
        const bf16x8 kf0 = *reinterpret_cast<const bf16x8*>(kr + ((l4 * 16) ^ sw));
        const bf16x8 kf1 = *reinterpret_cast<const bf16x8*>(kr + ((64 + l4 * 16) ^ sw));
        f32x4 a = (f32x4){0.f, 0.f, 0.f, 0.f};
        a = __builtin_amdgcn_mfma_f32_16x16x32_bf16(kf0, qfA0, a, 0, 0, 0);
        a = __builtin_amdgcn_mfma_f32_16x16x32_bf16(kf1, qfA1, a, 0, 0, 0);
        sA[hi] = a;
        f32x4 b = (f32x4){0.f, 0.f, 0.f, 0.f};
        b = __builtin_amdgcn_mfma_f32_16x16x32_bf16(kf0, qfB0, b, 0, 0, 0);
        b = __builtin_amdgcn_mfma_f32_16x16x32_bf16(kf1, qfB1, b, 0, 0, 0);
        sB[hi] = b;
      }
      bf16x8 pbA, pbB;
#pragma unroll
      for (int j = 0; j < 8; j++) {  // j = hi*4 + r
        pbA[j] = (bf16)exp2f(sA[j >> 2][j & 3]);
        pbB[j] = (bf16)exp2f(sB[j >> 2][j & 3]);
      }
#pragma unroll
      for (int dt = 0; dt < 4; dt++) {
        const bf16x8 vf = *reinterpret_cast<const bf16x8*>(
            VtB + (dt * 16 + l15) * 256 + (((kc * 4 + l4) ^ (l15 & 7)) << 4));
        accOA[dt] = __builtin_amdgcn_mfma_f32_16x16x32_bf16(vf, pbA, accOA[dt], 0, 0, 0);
        accOB[dt] = __builtin_amdgcn_mfma_f32_16x16x32_bf16(vf, pbB, accOB[dt], 0, 0, 0);
      }
      accLA = __builtin_amdgcn_mfma_f32_16x16x32_bf16(ones, pbA, accLA, 0, 0, 0);
      accLB = __builtin_amdgcn_mfma_f32_16x16x32_bf16(ones, pbB, accLB, 0, 0, 0);
    }
  }
#undef LOADKV

  // ---- epilogue: O^T layout col=l15=q, row=l4*4+r = d-within-tile
  const float invA = 1.0f / accLA[0];
  const float invB = 1.0f / accLB[0];
#pragma unroll
  for (int dt = 0; dt < 4; dt++) {
    const bf16x4 oA = (bf16x4){(bf16)(accOA[dt][0] * invA), (bf16)(accOA[dt][1] * invA),
                               (bf16)(accOA[dt][2] * invA), (bf16)(accOA[dt][3] * invA)};
    *reinterpret_cast<bf16x4*>(out + (size_t)(qbase + l15) * C_EMB + h * 64 + dt * 16 + l4 * 4) = oA;
    const bf16x4 oB = (bf16x4){(bf16)(accOB[dt][0] * invB), (bf16)(accOB[dt][1] * invB),
                               (bf16)(accOB[dt][2] * invB), (bf16)(accOB[dt][3] * invB)};
    *reinterpret_cast<bf16x4*>(out + (size_t)(qbase + 16 + l15) * C_EMB + h * 64 + dt * 16 + l4 * 4) = oB;
  }
}

// ------------------------------------------------------------------ launch
extern "C" void kernel_launch(void* const* d_in, const int* in_sizes, int n_in,
                              void* d_out, int out_size, void* d_ws, size_t ws_size,
                              hipStream_t stream) {
  const float* x       = (const float*)d_in[0];
  const float* W_kqv   = (const float*)d_in[1];
  const float* W_proj  = (const float*)d_in[2];
  const float* W_fc    = (const float*)d_in[3];
  const float* b_fc    = (const float*)d_in[4];
  const float* W_cproj = (const float*)d_in[5];
  float* outp = (float*)d_out;

  char* p = (char*)d_ws;
  bf16* Wkqv_t  = (bf16*)p; p += (size_t)2304 * 768 * 2;
  bf16* Wproj_t = (bf16*)p; p += (size_t)768 * 768 * 2;
  bf16* Wfc_t   = (bf16*)p; p += (size_t)1536 * 768 * 2;
  bf16* Wcp_t   = (bf16*)p; p += (size_t)768 * 1536 * 2;
  bf16* A1      = (bf16*)p; p += (size_t)4096 * 768 * 2;   // aliased: attn_out
  bf16* KQV     = (bf16*)p; p += (size_t)4096 * 2304 * 2;  // aliased: A2 | Hg
  float* x1     = (float*)p; p += (size_t)4096 * 768 * 4;
  bf16* attn_o = A1;
  bf16* A2     = KQV;
  bf16* Hg     = KQV + (size_t)4096 * 768;

  // weights: f32 [K][N] -> bf16 [N][K]
  wt_transpose<<<dim3(2304 / 32, 768 / 32), 256, 0, stream>>>(W_kqv, Wkqv_t, 768, 2304);
  wt_transpose<<<dim3(768 / 32, 768 / 32), 256, 0, stream>>>(W_proj, Wproj_t, 768, 768);
  wt_transpose<<<dim3(1536 / 32, 768 / 32), 256, 0, stream>>>(W_fc, Wfc_t, 768, 1536);
  wt_transpose<<<dim3(768 / 32, 1536 / 32), 256, 0, stream>>>(W_cproj, Wcp_t, 1536, 768);

  ln_rows<<<4096, 256, 0, stream>>>(x, A1);
  gemm_bt<0><<<dim3(32, 18), 256, 0, stream>>>(A1, Wkqv_t, KQV, nullptr, nullptr,
                                               4096, 2304, 768);
  attn_fused<<<dim3(64, 12), 128, 0, stream>>>(KQV, attn_o);
  gemm_bt<1><<<dim3(32, 6), 256, 0, stream>>>(attn_o, Wproj_t, x1, x, nullptr,
                                              4096, 768, 768);
  ln_rows<<<4096, 256, 0, stream>>>(x1, A2);
  gemm_bt<2><<<dim3(32, 12), 256, 0, stream>>>(A2, Wfc_t, Hg, nullptr, b_fc,
                                               4096, 1536, 768);
  gemm_bt<3><<<dim3(32, 6), 256, 0, stream>>>(Hg, Wcp_t, outp, x1, nullptr,
                                              4096, 768, 1536);
}

// Round 7
// 232.996 us; speedup vs baseline: 1.1089x; 1.1089x over previous
//
#include <hip/hip_runtime.h>
#include <hip/hip_bf16.h>
#include <math.h>

#define T_SEQ 4096
#define C_EMB 768
#define NHEAD 12
#define HDIM  64

typedef __bf16 bf16;
typedef __bf16 bf16x8 __attribute__((ext_vector_type(8)));
typedef __bf16 bf16x4 __attribute__((ext_vector_type(4)));
typedef float  f32x4  __attribute__((ext_vector_type(4)));

// ---------------------------------------------------------------- utilities

__device__ __forceinline__ void stage16(const void* g, void* ldsbase) {
  // global -> LDS direct, 16B per lane; LDS dest = wave-uniform base + lane*16
  __builtin_amdgcn_global_load_lds(
      (__attribute__((address_space(1))) const unsigned int*)g,
      (__attribute__((address_space(3))) unsigned int*)ldsbase, 16, 0, 0);
}

// -------------------------------------------------- weight convert+transpose
// W [K][N] f32  ->  Wt [N][K] bf16
__global__ void wt_transpose(const float* __restrict__ W, bf16* __restrict__ Wt,
                             int K, int N) {
  __shared__ float tile[32][33];
  const int n0 = blockIdx.x * 32, k0 = blockIdx.y * 32;
  const int tx = threadIdx.x & 31, ty = threadIdx.x >> 5;  // 256 thr: ty 0..7
#pragma unroll
  for (int i = 0; i < 32; i += 8)
    tile[ty + i][tx] = W[(size_t)(k0 + ty + i) * N + n0 + tx];
  __syncthreads();
#pragma unroll
  for (int i = 0; i < 32; i += 8)
    Wt[(size_t)(n0 + ty + i) * K + k0 + tx] = (bf16)tile[tx][ty + i];
}

// ------------------------------------------------------------------ layernorm
// x [4096][768] f32 -> y bf16
__global__ void ln_rows(const float* __restrict__ x, bf16* __restrict__ y) {
  const int row = blockIdx.x;
  const float* xr = x + (size_t)row * C_EMB;
  const int t = threadIdx.x;  // 256
  float v0 = xr[t], v1 = xr[t + 256], v2 = xr[t + 512];
  float s  = v0 + v1 + v2;
  float ss = v0 * v0 + v1 * v1 + v2 * v2;
#pragma unroll
  for (int m = 1; m < 64; m <<= 1) {
    s += __shfl_xor(s, m);
    ss += __shfl_xor(ss, m);
  }
  __shared__ float bs[4], bq[4];
  const int w = t >> 6;
  if ((t & 63) == 0) { bs[w] = s; bq[w] = ss; }
  __syncthreads();
  s  = bs[0] + bs[1] + bs[2] + bs[3];
  ss = bq[0] + bq[1] + bq[2] + bq[3];
  const float mu  = s * (1.0f / C_EMB);
  const float var = ss * (1.0f / C_EMB) - mu * mu;
  const float rs  = rsqrtf(var + 1e-5f);
  bf16* yr = y + (size_t)row * C_EMB;
  yr[t]       = (bf16)((v0 - mu) * rs);
  yr[t + 256] = (bf16)((v1 - mu) * rs);
  yr[t + 512] = (bf16)((v2 - mu) * rs);
}

// ------------------------------------------------------------------ GEMM
// C[M][N] = A[M][K](bf16 rowmajor) x BT[N][K](bf16)   (i.e. A @ B)
// Simple single-buffer m97 pattern. Measured best (R2/R3/R6): explicit
// dbuf/pipelining REGRESSED (R4/R5) -- implicit multi-block overlap already
// hides staging latency at 3-4 blocks/CU (guide Common-mistake #5).
// EPI 0: store bf16        EPI 1: f32 = res + acc
// EPI 2: bf16 = gelu(acc + bias[c])   EPI 3: f32 = res + acc
template <int EPI>
__global__ void gemm_bt(const bf16* __restrict__ A, const bf16* __restrict__ BT,
                        void* __restrict__ Cout, const float* __restrict__ res,
                        const float* __restrict__ bias, int M, int N, int K) {
  __shared__ __align__(16) bf16 As[128 * 32];
  __shared__ __align__(16) bf16 Bs[128 * 32];
  const int row0 = blockIdx.x * 128, col0 = blockIdx.y * 128;
  const int tid = threadIdx.x;
  const int w = tid >> 6, lane = tid & 63;
  const int wr = w >> 1, wc = w & 1;
  const int l15 = lane & 15, l4 = lane >> 4;

  f32x4 acc[4][4];
#pragma unroll
  for (int m = 0; m < 4; m++)
#pragma unroll
    for (int n = 0; n < 4; n++) acc[m][n] = (f32x4){0.f, 0.f, 0.f, 0.f};

  const int rr = lane >> 2;        // 16 rows per 1KB wave-instr
  const int c8 = (lane & 3) * 8;   // 4 chunks of 8 bf16 per 64B row

  for (int k0 = 0; k0 < K; k0 += 32) {
    const bf16* gA = A + (size_t)(row0 + w * 32 + rr) * K + k0 + c8;
    const bf16* gB = BT + (size_t)(col0 + w * 32 + rr) * K + k0 + c8;
    stage16(gA, As + (w * 32) * 32);
    stage16(gA + (size_t)16 * K, As + (w * 32 + 16) * 32);
    stage16(gB, Bs + (w * 32) * 32);
    stage16(gB + (size_t)16 * K, Bs + (w * 32 + 16) * 32);
    __syncthreads();

    bf16x8 af[4], bfv[4];
#pragma unroll
    for (int m = 0; m < 4; m++)
      af[m] = *reinterpret_cast<const bf16x8*>(As + (wr * 64 + m * 16 + l15) * 32 + l4 * 8);
#pragma unroll
    for (int n = 0; n < 4; n++)
      bfv[n] = *reinterpret_cast<const bf16x8*>(Bs + (wc * 64 + n * 16 + l15) * 32 + l4 * 8);
#pragma unroll
    for (int m = 0; m < 4; m++)
#pragma unroll
      for (int n = 0; n < 4; n++)
        acc[m][n] = __builtin_amdgcn_mfma_f32_16x16x32_bf16(af[m], bfv[n], acc[m][n], 0, 0, 0);
    __syncthreads();
  }

  const int orow = row0 + wr * 64;
  const int ocol = col0 + wc * 64;
#pragma unroll
  for (int m = 0; m < 4; m++) {
#pragma unroll
    for (int n = 0; n < 4; n++) {
      const int c = ocol + n * 16 + l15;
#pragma unroll
      for (int j = 0; j < 4; j++) {
        const int r = orow + m * 16 + l4 * 4 + j;  // C/D: col=lane&15, row=(lane>>4)*4+reg
        const size_t idx = (size_t)r * N + c;
        const float v = acc[m][n][j];
        if (EPI == 0) {
          ((bf16*)Cout)[idx] = (bf16)v;
        } else if (EPI == 1) {
          ((float*)Cout)[idx] = res[idx] + v;
        } else if (EPI == 2) {
          const float h = v + bias[c];
          ((bf16*)Cout)[idx] = (bf16)(0.5f * h * (1.0f + erff(h * 0.70710678118f)));
        } else {
          ((float*)Cout)[idx] = res[idx] + v;
        }
      }
    }
  }
}

// ------------------------------------------------------------------ attention
// kqv [T][2304] bf16 : k at +0, q at +768, v at +1536, head offset h*64
// Writes UNNORMALIZED partials:  Opart[half][4096][768] f32,
//                                Lpart[half][12][4096]  f32.
// grid (64 qb, 12 h, 2 kv-half): key-split doubles the grid (768 -> 1536
// blocks = 6/CU) because R5/R6 showed the kernel is occupancy-bound, and the
// 3-blocks/CU grid was the cap. No-max softmax (P = exp2(st), |st| << 127)
// makes partials EXACTLY additive: O = sum(accO) / sum(accL).
//
// Block = 4 waves x 16 q-rows (QB=64); KV tile = 128 keys, 16 iterations.
// Swapped QK^T (S^T = mfma(K,Q)); Q pre-scaled by 0.125*log2e.
// lrun via MFMA ones-trick. Key-relabel: position p holds key label
// l(p) = bit-perm [b5 b4 b3 b2 | b6 | b1 b0] of p; V stored at Vt[d][l(p)]
// so the PV B-frag is lane-local. K/V reg-staged with cross-iter prefetch.
__global__ void attn_fused(const bf16* __restrict__ kqv,
                           float* __restrict__ Opart,
                           float* __restrict__ Lpart) {
  const int qb = blockIdx.x, h = blockIdx.y, half = blockIdx.z;
  const int tid = threadIdx.x, w = tid >> 6, lane = tid & 63;
  const int l15 = lane & 15, l4 = lane >> 4;

  __shared__ __align__(16) bf16 Ks[128 * 64];   // [pos][d], chunk ^ (pos&7)
  __shared__ __align__(16) bf16 Vt[64 * 128];   // [d][label], chunk ^ (d&7)
  char* const KsB = (char*)Ks;
  char* const VtB = (char*)Vt;

  // Q fragments (B operand), pre-scaled by scale*log2(e)
  const int qrow = qb * 64 + w * 16 + l15;
  const bf16* qp = kqv + (size_t)qrow * 2304 + 768 + h * 64 + l4 * 8;
  bf16x8 qf0 = *reinterpret_cast<const bf16x8*>(qp);
  bf16x8 qf1 = *reinterpret_cast<const bf16x8*>(qp + 32);
  const float cscale = 0.125f * 1.4426950408889634f;
#pragma unroll
  for (int e = 0; e < 8; e++) {
    qf0[e] = (bf16)((float)qf0[e] * cscale);
    qf1[e] = (bf16)((float)qf1[e] * cscale);
  }
  bf16x8 ones;
#pragma unroll
  for (int e = 0; e < 8; e++) ones[e] = (bf16)1.0f;

  f32x4 accL = (f32x4){0.f, 0.f, 0.f, 0.f};
  f32x4 accO[4];
#pragma unroll
  for (int dt = 0; dt < 4; dt++) accO[dt] = (f32x4){0.f, 0.f, 0.f, 0.f};

  // K staging ownership: row = tid>>1 (0..127), 64B half = tid&1
  const int krow = tid >> 1;
  const int kc0 = (tid & 1) * 4;
  const int swK = krow & 7;
  // V staging ownership: keys kb*4..+3, d = db*8..+7; label base of kb*4
  const int kb = tid & 31, db = tid >> 5;
  const int lb = ((kb >> 2) & 3) * 32 + (kb & 3) * 8 + (kb >> 4) * 4;
  const int lchunk = lb >> 3, lbyte = (lb & 7) * 2;

  const int kt0 = half * 16;  // this block's 16 key-tiles: kt0 .. kt0+15

  bf16x8 kreg0, kreg1, kreg2, kreg3, vreg0, vreg1, vreg2, vreg3;
#define LOADKV(kt)                                                              \
  {                                                                             \
    const bf16* kp = kqv + (size_t)((kt)*128 + krow) * 2304 + h * 64 + kc0 * 8; \
    kreg0 = *reinterpret_cast<const bf16x8*>(kp);                               \
    kreg1 = *reinterpret_cast<const bf16x8*>(kp + 8);                           \
    kreg2 = *reinterpret_cast<const bf16x8*>(kp + 16);                          \
    kreg3 = *reinterpret_cast<const bf16x8*>(kp + 24);                          \
    const bf16* vp =                                                            \
        kqv + (size_t)((kt)*128 + kb * 4) * 2304 + 1536 + h * 64 + db * 8;      \
    vreg0 = *reinterpret_cast<const bf16x8*>(vp);                               \
    vreg1 = *reinterpret_cast<const bf16x8*>(vp + 2304);                        \
    vreg2 = *reinterpret_cast<const bf16x8*>(vp + 4608);                        \
    vreg3 = *reinterpret_cast<const bf16x8*>(vp + 6912);                        \
  }

  LOADKV(kt0);
  const int sw = (l15 & 7) << 4;

  for (int kt = 0; kt < 16; kt++) {
    __syncthreads();
    // ---- LDS writes from registers (no global latency inside barriers)
    {
      char* kdst = KsB + krow * 128;
      *reinterpret_cast<bf16x8*>(kdst + (((kc0 + 0) ^ swK) << 4)) = kreg0;
      *reinterpret_cast<bf16x8*>(kdst + (((kc0 + 1) ^ swK) << 4)) = kreg1;
      *reinterpret_cast<bf16x8*>(kdst + (((kc0 + 2) ^ swK) << 4)) = kreg2;
      *reinterpret_cast<bf16x8*>(kdst + (((kc0 + 3) ^ swK) << 4)) = kreg3;
#pragma unroll
      for (int e = 0; e < 8; e++) {
        const int d = db * 8 + e;
        const bf16x4 pk4 = (bf16x4){vreg0[e], vreg1[e], vreg2[e], vreg3[e]};
        *reinterpret_cast<bf16x4*>(VtB + d * 256 + ((lchunk ^ (d & 7)) << 4) + lbyte) = pk4;
      }
    }
    __syncthreads();
    if (kt + 1 < 16) LOADKV(kt0 + kt + 1);  // prefetch flies during compute

    // ---- S^T = K @ Q^T (log2 domain already; C-init 0)
    f32x4 st[8];
#pragma unroll
    for (int t = 0; t < 8; t++) {
      const char* kr = KsB + (16 * t + l15) * 128;
      const bf16x8 kf0 = *reinterpret_cast<const bf16x8*>(kr + ((l4 * 16) ^ sw));
      const bf16x8 kf1 = *reinterpret_cast<const bf16x8*>(kr + ((64 + l4 * 16) ^ sw));
      f32x4 a = (f32x4){0.f, 0.f, 0.f, 0.f};
      a = __builtin_amdgcn_mfma_f32_16x16x32_bf16(kf0, qf0, a, 0, 0, 0);
      a = __builtin_amdgcn_mfma_f32_16x16x32_bf16(kf1, qf1, a, 0, 0, 0);
      st[t] = a;
    }

    // ---- no-max softmax: P = exp2(st) directly
#pragma unroll
    for (int t = 0; t < 8; t++)
#pragma unroll
      for (int r = 0; r < 4; r++) st[t][r] = exp2f(st[t][r]);

    // ---- O^T += V^T @ P^T ; accL += ones @ P^T (row-sum in every lane)
#pragma unroll
    for (int kc = 0; kc < 4; kc++) {
      bf16x8 pb;
      pb[0] = (bf16)st[kc][0];
      pb[1] = (bf16)st[kc][1];
      pb[2] = (bf16)st[kc][2];
      pb[3] = (bf16)st[kc][3];
      pb[4] = (bf16)st[kc + 4][0];
      pb[5] = (bf16)st[kc + 4][1];
      pb[6] = (bf16)st[kc + 4][2];
      pb[7] = (bf16)st[kc + 4][3];
#pragma unroll
      for (int dt = 0; dt < 4; dt++) {
        const bf16x8 vf = *reinterpret_cast<const bf16x8*>(
            VtB + (dt * 16 + l15) * 256 + (((kc * 4 + l4) ^ (l15 & 7)) << 4));
        accO[dt] = __builtin_amdgcn_mfma_f32_16x16x32_bf16(vf, pb, accO[dt], 0, 0, 0);
      }
      accL = __builtin_amdgcn_mfma_f32_16x16x32_bf16(ones, pb, accL, 0, 0, 0);
    }
  }
#undef LOADKV

  // ---- epilogue: write unnormalized partials (f32)
  float* Oq = Opart + (size_t)half * T_SEQ * C_EMB + (size_t)qrow * C_EMB + h * 64;
#pragma unroll
  for (int dt = 0; dt < 4; dt++)
    *reinterpret_cast<f32x4*>(Oq + dt * 16 + l4 * 4) = accO[dt];
  if (l4 == 0)
    Lpart[(size_t)half * NHEAD * T_SEQ + (size_t)h * T_SEQ + qrow] = accL[0];
}

// ------------------------------------------------------- attention combine
// out[q][c] = (O0[q][c] + O1[q][c]) / (L0[h][q] + L1[h][q]),  h = c/64
__global__ void attn_combine(const float* __restrict__ Opart,
                             const float* __restrict__ Lpart,
                             bf16* __restrict__ out) {
  const int q = blockIdx.x, t = threadIdx.x;  // 256 threads
  const float* O0 = Opart + (size_t)q * C_EMB;
  const float* O1 = O0 + (size_t)T_SEQ * C_EMB;
#pragma unroll
  for (int i = 0; i < 3; i++) {
    const int c = t + i * 256;
    const int h = c >> 6;
    const float L = Lpart[(size_t)h * T_SEQ + q] +
                    Lpart[(size_t)NHEAD * T_SEQ + (size_t)h * T_SEQ + q];
    out[(size_t)q * C_EMB + c] = (bf16)((O0[c] + O1[c]) / L);
  }
}

// ------------------------------------------------------------------ launch
extern "C" void kernel_launch(void* const* d_in, const int* in_sizes, int n_in,
                              void* d_out, int out_size, void* d_ws, size_t ws_size,
                              hipStream_t stream) {
  const float* x       = (const float*)d_in[0];
  const float* W_kqv   = (const float*)d_in[1];
  const float* W_proj  = (const float*)d_in[2];
  const float* W_fc    = (const float*)d_in[3];
  const float* b_fc    = (const float*)d_in[4];
  const float* W_cproj = (const float*)d_in[5];
  float* outp = (float*)d_out;

  char* p = (char*)d_ws;
  bf16* Wkqv_t  = (bf16*)p; p += (size_t)2304 * 768 * 2;
  bf16* Wproj_t = (bf16*)p; p += (size_t)768 * 768 * 2;
  bf16* Wfc_t   = (bf16*)p; p += (size_t)1536 * 768 * 2;
  bf16* Wcp_t   = (bf16*)p; p += (size_t)768 * 1536 * 2;
  bf16* A1      = (bf16*)p; p += (size_t)4096 * 768 * 2;   // aliased: attn_out
  bf16* KQV     = (bf16*)p; p += (size_t)4096 * 2304 * 2;  // aliased: A2 | Hg
  float* x1     = (float*)p; p += (size_t)4096 * 768 * 4;
  // attn partials: half 0 aliases x1 (x1 is written AFTER combine consumed
  // the partials, by the proj GEMM); half 1 + Lpart are fresh ws.
  float* Opart  = x1;       p += (size_t)4096 * 768 * 4;   // half 1
  float* Lpart  = (float*)p; p += (size_t)2 * NHEAD * 4096 * 4;
  bf16* attn_o = A1;
  bf16* A2     = KQV;
  bf16* Hg     = KQV + (size_t)4096 * 768;

  // weights: f32 [K][N] -> bf16 [N][K]
  wt_transpose<<<dim3(2304 / 32, 768 / 32), 256, 0, stream>>>(W_kqv, Wkqv_t, 768, 2304);
  wt_transpose<<<dim3(768 / 32, 768 / 32), 256, 0, stream>>>(W_proj, Wproj_t, 768, 768);
  wt_transpose<<<dim3(1536 / 32, 768 / 32), 256, 0, stream>>>(W_fc, Wfc_t, 768, 1536);
  wt_transpose<<<dim3(768 / 32, 1536 / 32), 256, 0, stream>>>(W_cproj, Wcp_t, 1536, 768);

  ln_rows<<<4096, 256, 0, stream>>>(x, A1);
  gemm_bt<0><<<dim3(32, 18), 256, 0, stream>>>(A1, Wkqv_t, KQV, nullptr, nullptr,
                                               4096, 2304, 768);
  attn_fused<<<dim3(64, 12, 2), 256, 0, stream>>>(KQV, Opart, Lpart);
  attn_combine<<<4096, 256, 0, stream>>>(Opart, Lpart, attn_o);
  gemm_bt<1><<<dim3(32, 6), 256, 0, stream>>>(attn_o, Wproj_t, x1, x, nullptr,
                                              4096, 768, 768);
  ln_rows<<<4096, 256, 0, stream>>>(x1, A2);
  gemm_bt<2><<<dim3(32, 12), 256, 0, stream>>>(A2, Wfc_t, Hg, nullptr, b_fc,
                                               4096, 1536, 768);
  gemm_bt<3><<<dim3(32, 6), 256, 0, stream>>>(Hg, Wcp_t, outp, x1, nullptr,
                                              4096, 768, 1536);
}

// Round 8
// 231.947 us; speedup vs baseline: 1.1139x; 1.0045x over previous
//
#include <hip/hip_runtime.h>
#include <hip/hip_bf16.h>
#include <math.h>

#define T_SEQ 4096
#define C_EMB 768
#define NHEAD 12
#define HDIM  64

typedef __bf16 bf16;
typedef __bf16 bf16x8 __attribute__((ext_vector_type(8)));
typedef __bf16 bf16x4 __attribute__((ext_vector_type(4)));
typedef float  f32x4  __attribute__((ext_vector_type(4)));

// ---------------------------------------------------------------- utilities

__device__ __forceinline__ void stage16(const void* g, void* ldsbase) {
  // global -> LDS direct, 16B per lane; LDS dest = wave-uniform base + lane*16
  __builtin_amdgcn_global_load_lds(
      (__attribute__((address_space(1))) const unsigned int*)g,
      (__attribute__((address_space(3))) unsigned int*)ldsbase, 16, 0, 0);
}

// -------------------------------------------------- weight convert+transpose
// W [K][N] f32  ->  Wt [N][K] bf16
__global__ void wt_transpose(const float* __restrict__ W, bf16* __restrict__ Wt,
                             int K, int N) {
  __shared__ float tile[32][33];
  const int n0 = blockIdx.x * 32, k0 = blockIdx.y * 32;
  const int tx = threadIdx.x & 31, ty = threadIdx.x >> 5;  // 256 thr: ty 0..7
#pragma unroll
  for (int i = 0; i < 32; i += 8)
    tile[ty + i][tx] = W[(size_t)(k0 + ty + i) * N + n0 + tx];
  __syncthreads();
#pragma unroll
  for (int i = 0; i < 32; i += 8)
    Wt[(size_t)(n0 + ty + i) * K + k0 + tx] = (bf16)tile[tx][ty + i];
}

// ------------------------------------------------------------------ layernorm
// x [4096][768] f32 -> y bf16
__global__ void ln_rows(const float* __restrict__ x, bf16* __restrict__ y) {
  const int row = blockIdx.x;
  const float* xr = x + (size_t)row * C_EMB;
  const int t = threadIdx.x;  // 256
  float v0 = xr[t], v1 = xr[t + 256], v2 = xr[t + 512];
  float s  = v0 + v1 + v2;
  float ss = v0 * v0 + v1 * v1 + v2 * v2;
#pragma unroll
  for (int m = 1; m < 64; m <<= 1) {
    s += __shfl_xor(s, m);
    ss += __shfl_xor(ss, m);
  }
  __shared__ float bs[4], bq[4];
  const int w = t >> 6;
  if ((t & 63) == 0) { bs[w] = s; bq[w] = ss; }
  __syncthreads();
  s  = bs[0] + bs[1] + bs[2] + bs[3];
  ss = bq[0] + bq[1] + bq[2] + bq[3];
  const float mu  = s * (1.0f / C_EMB);
  const float var = ss * (1.0f / C_EMB) - mu * mu;
  const float rs  = rsqrtf(var + 1e-5f);
  bf16* yr = y + (size_t)row * C_EMB;
  yr[t]       = (bf16)((v0 - mu) * rs);
  yr[t + 256] = (bf16)((v1 - mu) * rs);
  yr[t + 512] = (bf16)((v2 - mu) * rs);
}

// ------------------------------------------------------------------ GEMM
// C[M][N] = A[M][K](bf16 rowmajor) x BT[N][K](bf16)   (i.e. A @ B)
// Single-buffer m97 pattern (R4/R5 pipelining regressed), BK=64: halves the
// barrier count vs BK=32 (32 MFMAs between barriers instead of 16), LDS 32KB
// still allows ~5 blocks/CU.
// EPI 0: store bf16        EPI 1: f32 = res + acc
// EPI 2: bf16 = gelu(acc + bias[c])   EPI 3: f32 = res + acc
template <int EPI>
__global__ void gemm_bt(const bf16* __restrict__ A, const bf16* __restrict__ BT,
                        void* __restrict__ Cout, const float* __restrict__ res,
                        const float* __restrict__ bias, int M, int N, int K) {
  __shared__ __align__(16) bf16 As[128 * 64];
  __shared__ __align__(16) bf16 Bs[128 * 64];
  const int row0 = blockIdx.x * 128, col0 = blockIdx.y * 128;
  const int tid = threadIdx.x;
  const int w = tid >> 6, lane = tid & 63;
  const int wr = w >> 1, wc = w & 1;
  const int l15 = lane & 15, l4 = lane >> 4;

  f32x4 acc[4][4];
#pragma unroll
  for (int m = 0; m < 4; m++)
#pragma unroll
    for (int n = 0; n < 4; n++) acc[m][n] = (f32x4){0.f, 0.f, 0.f, 0.f};

  const int rr = lane >> 3;        // 8 rows per 1KB wave-instr (128B rows)
  const int c8 = (lane & 7) * 8;   // 8 chunks of 8 bf16 per 128B row

  for (int k0 = 0; k0 < K; k0 += 64) {
    const bf16* gA = A + (size_t)(row0 + w * 32 + rr) * K + k0 + c8;
    const bf16* gB = BT + (size_t)(col0 + w * 32 + rr) * K + k0 + c8;
#pragma unroll
    for (int i = 0; i < 4; i++) {
      stage16(gA + (size_t)(8 * i) * K, As + (w * 32 + 8 * i) * 64);
      stage16(gB + (size_t)(8 * i) * K, Bs + (w * 32 + 8 * i) * 64);
    }
    __syncthreads();

#pragma unroll
    for (int hh = 0; hh < 2; hh++) {
      bf16x8 af[4], bfv[4];
#pragma unroll
      for (int m = 0; m < 4; m++)
        af[m] = *reinterpret_cast<const bf16x8*>(
            As + (wr * 64 + m * 16 + l15) * 64 + hh * 32 + l4 * 8);
#pragma unroll
      for (int n = 0; n < 4; n++)
        bfv[n] = *reinterpret_cast<const bf16x8*>(
            Bs + (wc * 64 + n * 16 + l15) * 64 + hh * 32 + l4 * 8);
#pragma unroll
      for (int m = 0; m < 4; m++)
#pragma unroll
        for (int n = 0; n < 4; n++)
          acc[m][n] = __builtin_amdgcn_mfma_f32_16x16x32_bf16(af[m], bfv[n], acc[m][n], 0, 0, 0);
    }
    __syncthreads();
  }

  const int orow = row0 + wr * 64;
  const int ocol = col0 + wc * 64;
#pragma unroll
  for (int m = 0; m < 4; m++) {
#pragma unroll
    for (int n = 0; n < 4; n++) {
      const int c = ocol + n * 16 + l15;
#pragma unroll
      for (int j = 0; j < 4; j++) {
        const int r = orow + m * 16 + l4 * 4 + j;  // C/D: col=lane&15, row=(lane>>4)*4+reg
        const size_t idx = (size_t)r * N + c;
        const float v = acc[m][n][j];
        if (EPI == 0) {
          ((bf16*)Cout)[idx] = (bf16)v;
        } else if (EPI == 1) {
          ((float*)Cout)[idx] = res[idx] + v;
        } else if (EPI == 2) {
          const float h = v + bias[c];
          ((bf16*)Cout)[idx] = (bf16)(0.5f * h * (1.0f + erff(h * 0.70710678118f)));
        } else {
          ((float*)Cout)[idx] = res[idx] + v;
        }
      }
    }
  }
}

// ------------------------------------------------------------------ attention
// kqv [T][2304] bf16 : k at +0, q at +768, v at +1536, head offset h*64
// Writes UNNORMALIZED partials:  Opart[half][4096][768] f32,
//                                Lpart[half][12][4096]  f32.
// grid (64 qb, 12 h, 2 kv-half); no-max softmax (P = exp2(st), |st| << 127)
// makes partials EXACTLY additive: O = sum(accO) / sum(accL).
//
// Block = 4 waves x 16 q-rows (QB=64); KV tile = 128 keys, 16 iterations.
// Swapped QK^T (S^T = mfma(K,Q)); Q pre-scaled by 0.125*log2e.
// Compute is 4 per-32-key SUB-ROUNDS (QK 2 tiles -> exp2 -> PV): only 2 f32x4
// of softmax state live (vs 8), and each sub-round's exp2-trans chain overlaps
// the next one's ds_read+MFMA in the scheduler.
// Key-relabel (R6-verified): position p = 32kc+16hi+4g+r holds key label
// l = 32kc+8g+4hi+r, so the PV B-frag is lane-local: pb[hi*4+r] = exp2(s[hi][r]).
// V is scattered to Vt[d][label] during staging; K/V reg-staged with
// cross-iteration prefetch. lrun via MFMA ones-trick.
__global__ void attn_fused(const bf16* __restrict__ kqv,
                           float* __restrict__ Opart,
                           float* __restrict__ Lpart) {
  const int qb = blockIdx.x, h = blockIdx.y, half = blockIdx.z;
  const int tid = threadIdx.x, w = tid >> 6, lane = tid & 63;
  const int l15 = lane & 15, l4 = lane >> 4;

  __shared__ __align__(16) bf16 Ks[128 * 64];   // [pos][d], chunk ^ (pos&7)
  __shared__ __align__(16) bf16 Vt[64 * 128];   // [d][label], chunk ^ (d&7)
  char* const KsB = (char*)Ks;
  char* const VtB = (char*)Vt;

  // Q fragments (B operand), pre-scaled by scale*log2(e)
  const int qrow = qb * 64 + w * 16 + l15;
  const bf16* qp = kqv + (size_t)qrow * 2304 + 768 + h * 64 + l4 * 8;
  bf16x8 qf0 = *reinterpret_cast<const bf16x8*>(qp);
  bf16x8 qf1 = *reinterpret_cast<const bf16x8*>(qp + 32);
  const float cscale = 0.125f * 1.4426950408889634f;
#pragma unroll
  for (int e = 0; e < 8; e++) {
    qf0[e] = (bf16)((float)qf0[e] * cscale);
    qf1[e] = (bf16)((float)qf1[e] * cscale);
  }
  bf16x8 ones;
#pragma unroll
  for (int e = 0; e < 8; e++) ones[e] = (bf16)1.0f;

  f32x4 accL = (f32x4){0.f, 0.f, 0.f, 0.f};
  f32x4 accO[4];
#pragma unroll
  for (int dt = 0; dt < 4; dt++) accO[dt] = (f32x4){0.f, 0.f, 0.f, 0.f};

  // K staging ownership: row = tid>>1 (0..127), 64B half = tid&1
  const int krow = tid >> 1;
  const int kc0 = (tid & 1) * 4;
  const int swK = krow & 7;
  // V staging ownership: keys kb*4..+3, d = db*8..+7
  // label base for key m=kb*4: l = 32*(m>>5) + 8*((m>>2)&3) + 4*((m>>4)&1)
  const int kb = tid & 31, db = tid >> 5;
  const int lb = ((kb & 0x18) << 2) | ((kb & 3) << 3) | (kb & 4);
  const int lchunk = lb >> 3, lbyte = (lb & 7) * 2;

  const int kt0 = half * 16;  // this block's 16 key-tiles: kt0 .. kt0+15

  bf16x8 kreg0, kreg1, kreg2, kreg3, vreg0, vreg1, vreg2, vreg3;
#define LOADKV(kt)                                                              \
  {                                                                             \
    const bf16* kp = kqv + (size_t)((kt)*128 + krow) * 2304 + h * 64 + kc0 * 8; \
    kreg0 = *reinterpret_cast<const bf16x8*>(kp);                               \
    kreg1 = *reinterpret_cast<const bf16x8*>(kp + 8);                           \
    kreg2 = *reinterpret_cast<const bf16x8*>(kp + 16);                          \
    kreg3 = *reinterpret_cast<const bf16x8*>(kp + 24);                          \
    const bf16* vp =                                                            \
        kqv + (size_t)((kt)*128 + kb * 4) * 2304 + 1536 + h * 64 + db * 8;      \
    vreg0 = *reinterpret_cast<const bf16x8*>(vp);                               \
    vreg1 = *reinterpret_cast<const bf16x8*>(vp + 2304);                        \
    vreg2 = *reinterpret_cast<const bf16x8*>(vp + 4608);                        \
    vreg3 = *reinterpret_cast<const bf16x8*>(vp + 6912);                        \
  }

  LOADKV(kt0);
  const int sw = (l15 & 7) << 4;

  for (int kt = 0; kt < 16; kt++) {
    __syncthreads();
    // ---- LDS writes from registers (no global latency inside barriers)
    {
      char* kdst = KsB + krow * 128;
      *reinterpret_cast<bf16x8*>(kdst + (((kc0 + 0) ^ swK) << 4)) = kreg0;
      *reinterpret_cast<bf16x8*>(kdst + (((kc0 + 1) ^ swK) << 4)) = kreg1;
      *reinterpret_cast<bf16x8*>(kdst + (((kc0 + 2) ^ swK) << 4)) = kreg2;
      *reinterpret_cast<bf16x8*>(kdst + (((kc0 + 3) ^ swK) << 4)) = kreg3;
#pragma unroll
      for (int e = 0; e < 8; e++) {
        const int d = db * 8 + e;
        const bf16x4 pk4 = (bf16x4){vreg0[e], vreg1[e], vreg2[e], vreg3[e]};
        *reinterpret_cast<bf16x4*>(VtB + d * 256 + ((lchunk ^ (d & 7)) << 4) + lbyte) = pk4;
      }
    }
    __syncthreads();
    if (kt + 1 < 16) LOADKV(kt0 + kt + 1);  // prefetch flies during compute

    // ---- 4 sub-rounds: QK (tiles 2kc,2kc+1) -> exp2 -> PV chunk kc
#pragma unroll
    for (int kc = 0; kc < 4; kc++) {
      f32x4 s0 = (f32x4){0.f, 0.f, 0.f, 0.f};
      f32x4 s1 = (f32x4){0.f, 0.f, 0.f, 0.f};
      {
        const char* kr0 = KsB + (16 * (2 * kc + 0) + l15) * 128;
        const bf16x8 ka = *reinterpret_cast<const bf16x8*>(kr0 + ((l4 * 16) ^ sw));
        const bf16x8 kb_ = *reinterpret_cast<const bf16x8*>(kr0 + ((64 + l4 * 16) ^ sw));
        s0 = __builtin_amdgcn_mfma_f32_16x16x32_bf16(ka, qf0, s0, 0, 0, 0);
        s0 = __builtin_amdgcn_mfma_f32_16x16x32_bf16(kb_, qf1, s0, 0, 0, 0);
        const char* kr1 = KsB + (16 * (2 * kc + 1) + l15) * 128;
        const bf16x8 kc_ = *reinterpret_cast<const bf16x8*>(kr1 + ((l4 * 16) ^ sw));
        const bf16x8 kd = *reinterpret_cast<const bf16x8*>(kr1 + ((64 + l4 * 16) ^ sw));
        s1 = __builtin_amdgcn_mfma_f32_16x16x32_bf16(kc_, qf0, s1, 0, 0, 0);
        s1 = __builtin_amdgcn_mfma_f32_16x16x32_bf16(kd, qf1, s1, 0, 0, 0);
      }
      bf16x8 pb;
      pb[0] = (bf16)exp2f(s0[0]);
      pb[1] = (bf16)exp2f(s0[1]);
      pb[2] = (bf16)exp2f(s0[2]);
      pb[3] = (bf16)exp2f(s0[3]);
      pb[4] = (bf16)exp2f(s1[0]);
      pb[5] = (bf16)exp2f(s1[1]);
      pb[6] = (bf16)exp2f(s1[2]);
      pb[7] = (bf16)exp2f(s1[3]);
#pragma unroll
      for (int dt = 0; dt < 4; dt++) {
        const bf16x8 vf = *reinterpret_cast<const bf16x8*>(
            VtB + (dt * 16 + l15) * 256 + (((kc * 4 + l4) ^ (l15 & 7)) << 4));
        accO[dt] = __builtin_amdgcn_mfma_f32_16x16x32_bf16(vf, pb, accO[dt], 0, 0, 0);
      }
      accL = __builtin_amdgcn_mfma_f32_16x16x32_bf16(ones, pb, accL, 0, 0, 0);
    }
  }
#undef LOADKV

  // ---- epilogue: write unnormalized partials (f32)
  float* Oq = Opart + (size_t)half * T_SEQ * C_EMB + (size_t)qrow * C_EMB + h * 64;
#pragma unroll
  for (int dt = 0; dt < 4; dt++)
    *reinterpret_cast<f32x4*>(Oq + dt * 16 + l4 * 4) = accO[dt];
  if (l4 == 0)
    Lpart[(size_t)half * NHEAD * T_SEQ + (size_t)h * T_SEQ + qrow] = accL[0];
}

// ------------------------------------------------------- attention combine
// out[q][c] = (O0[q][c] + O1[q][c]) / (L0[h][q] + L1[h][q]),  h = c/64
__global__ void attn_combine(const float* __restrict__ Opart,
                             const float* __restrict__ Lpart,
                             bf16* __restrict__ out) {
  const int q = blockIdx.x, t = threadIdx.x;  // 256 threads
  const float* O0 = Opart + (size_t)q * C_EMB;
  const float* O1 = O0 + (size_t)T_SEQ * C_EMB;
#pragma unroll
  for (int i = 0; i < 3; i++) {
    const int c = t + i * 256;
    const int h = c >> 6;
    const float L = Lpart[(size_t)h * T_SEQ + q] +
                    Lpart[(size_t)NHEAD * T_SEQ + (size_t)h * T_SEQ + q];
    out[(size_t)q * C_EMB + c] = (bf16)((O0[c] + O1[c]) / L);
  }
}

// ------------------------------------------------------------------ launch
extern "C" void kernel_launch(void* const* d_in, const int* in_sizes, int n_in,
                              void* d_out, int out_size, void* d_ws, size_t ws_size,
                              hipStream_t stream) {
  const float* x       = (const float*)d_in[0];
  const float* W_kqv   = (const float*)d_in[1];
  const float* W_proj  = (const float*)d_in[2];
  const float* W_fc    = (const float*)d_in[3];
  const float* b_fc    = (const float*)d_in[4];
  const float* W_cproj = (const float*)d_in[5];
  float* outp = (float*)d_out;

  char* p = (char*)d_ws;
  bf16* Wkqv_t  = (bf16*)p; p += (size_t)2304 * 768 * 2;
  bf16* Wproj_t = (bf16*)p; p += (size_t)768 * 768 * 2;
  bf16* Wfc_t   = (bf16*)p; p += (size_t)1536 * 768 * 2;
  bf16* Wcp_t   = (bf16*)p; p += (size_t)768 * 1536 * 2;
  bf16* A1      = (bf16*)p; p += (size_t)4096 * 768 * 2;   // aliased: attn_out
  bf16* KQV     = (bf16*)p; p += (size_t)4096 * 2304 * 2;  // aliased: A2 | Hg
  float* x1     = (float*)p; p += (size_t)4096 * 768 * 4;
  // attn partials: half 0 aliases x1 (x1 is written AFTER combine consumed
  // the partials, by the proj GEMM); half 1 + Lpart are fresh ws.
  float* Opart  = x1;       p += (size_t)4096 * 768 * 4;   // half 1
  float* Lpart  = (float*)p; p += (size_t)2 * NHEAD * 4096 * 4;
  bf16* attn_o = A1;
  bf16* A2     = KQV;
  bf16* Hg     = KQV + (size_t)4096 * 768;

  // weights: f32 [K][N] -> bf16 [N][K]
  wt_transpose<<<dim3(2304 / 32, 768 / 32), 256, 0, stream>>>(W_kqv, Wkqv_t, 768, 2304);
  wt_transpose<<<dim3(768 / 32, 768 / 32), 256, 0, stream>>>(W_proj, Wproj_t, 768, 768);
  wt_transpose<<<dim3(1536 / 32, 768 / 32), 256, 0, stream>>>(W_fc, Wfc_t, 768, 1536);
  wt_transpose<<<dim3(768 / 32, 1536 / 32), 256, 0, stream>>>(W_cproj, Wcp_t, 1536, 768);

  ln_rows<<<4096, 256, 0, stream>>>(x, A1);
  gemm_bt<0><<<dim3(32, 18), 256, 0, stream>>>(A1, Wkqv_t, KQV, nullptr, nullptr,
                                               4096, 2304, 768);
  attn_fused<<<dim3(64, 12, 2), 256, 0, stream>>>(KQV, Opart, Lpart);
  attn_combine<<<4096, 256, 0, stream>>>(Opart, Lpart, attn_o);
  gemm_bt<1><<<dim3(32, 6), 256, 0, stream>>>(attn_o, Wproj_t, x1, x, nullptr,
                                              4096, 768, 768);
  ln_rows<<<4096, 256, 0, stream>>>(x1, A2);
  gemm_bt<2><<<dim3(32, 12), 256, 0, stream>>>(A2, Wfc_t, Hg, nullptr, b_fc,
                                               4096, 1536, 768);
  gemm_bt<3><<<dim3(32, 6), 256, 0, stream>>>(Hg, Wcp_t, outp, x1, nullptr,
                                              4096, 768, 1536);
}

// Round 9
// 223.466 us; speedup vs baseline: 1.1562x; 1.0380x over previous
//
#include <hip/hip_runtime.h>
#include <hip/hip_bf16.h>
#include <math.h>

#define T_SEQ 4096
#define C_EMB 768
#define NHEAD 12
#define HDIM  64

typedef __bf16 bf16;
typedef __bf16 bf16x8 __attribute__((ext_vector_type(8)));
typedef __bf16 bf16x4 __attribute__((ext_vector_type(4)));
typedef float  f32x4  __attribute__((ext_vector_type(4)));
typedef float  f32x16 __attribute__((ext_vector_type(16)));

// ---------------------------------------------------------------- utilities

__device__ __forceinline__ void stage16(const void* g, void* ldsbase) {
  // global -> LDS direct, 16B per lane; LDS dest = wave-uniform base + lane*16
  __builtin_amdgcn_global_load_lds(
      (__attribute__((address_space(1))) const unsigned int*)g,
      (__attribute__((address_space(3))) unsigned int*)ldsbase, 16, 0, 0);
}

__device__ __forceinline__ f32x16 zero16() {
  f32x16 z;
#pragma unroll
  for (int i = 0; i < 16; i++) z[i] = 0.f;
  return z;
}

// -------------------------------------------------- weight convert+transpose
// W [K][N] f32  ->  Wt [N][K] bf16
__global__ void wt_transpose(const float* __restrict__ W, bf16* __restrict__ Wt,
                             int K, int N) {
  __shared__ float tile[32][33];
  const int n0 = blockIdx.x * 32, k0 = blockIdx.y * 32;
  const int tx = threadIdx.x & 31, ty = threadIdx.x >> 5;  // 256 thr: ty 0..7
#pragma unroll
  for (int i = 0; i < 32; i += 8)
    tile[ty + i][tx] = W[(size_t)(k0 + ty + i) * N + n0 + tx];
  __syncthreads();
#pragma unroll
  for (int i = 0; i < 32; i += 8)
    Wt[(size_t)(n0 + ty + i) * K + k0 + tx] = (bf16)tile[tx][ty + i];
}

// ------------------------------------------------------------------ layernorm
// x [4096][768] f32 -> y bf16
__global__ void ln_rows(const float* __restrict__ x, bf16* __restrict__ y) {
  const int row = blockIdx.x;
  const float* xr = x + (size_t)row * C_EMB;
  const int t = threadIdx.x;  // 256
  float v0 = xr[t], v1 = xr[t + 256], v2 = xr[t + 512];
  float s  = v0 + v1 + v2;
  float ss = v0 * v0 + v1 * v1 + v2 * v2;
#pragma unroll
  for (int m = 1; m < 64; m <<= 1) {
    s += __shfl_xor(s, m);
    ss += __shfl_xor(ss, m);
  }
  __shared__ float bs[4], bq[4];
  const int w = t >> 6;
  if ((t & 63) == 0) { bs[w] = s; bq[w] = ss; }
  __syncthreads();
  s  = bs[0] + bs[1] + bs[2] + bs[3];
  ss = bq[0] + bq[1] + bq[2] + bq[3];
  const float mu  = s * (1.0f / C_EMB);
  const float var = ss * (1.0f / C_EMB) - mu * mu;
  const float rs  = rsqrtf(var + 1e-5f);
  bf16* yr = y + (size_t)row * C_EMB;
  yr[t]       = (bf16)((v0 - mu) * rs);
  yr[t + 256] = (bf16)((v1 - mu) * rs);
  yr[t + 512] = (bf16)((v2 - mu) * rs);
}

// ------------------------------------------------------------------ GEMM
// C[M][N] = A[M][K](bf16 rowmajor) x BT[N][K](bf16)   (i.e. A @ B)
// Single-buffer m97 pattern, BK=64 (R8 measured; explicit pipelining
// regressed in R4/R5 -- implicit multi-block overlap already hides staging).
// EPI 0: store bf16        EPI 1: f32 = res + acc
// EPI 2: bf16 = gelu(acc + bias[c])   EPI 3: f32 = res + acc
template <int EPI>
__global__ void gemm_bt(const bf16* __restrict__ A, const bf16* __restrict__ BT,
                        void* __restrict__ Cout, const float* __restrict__ res,
                        const float* __restrict__ bias, int M, int N, int K) {
  __shared__ __align__(16) bf16 As[128 * 64];
  __shared__ __align__(16) bf16 Bs[128 * 64];
  const int row0 = blockIdx.x * 128, col0 = blockIdx.y * 128;
  const int tid = threadIdx.x;
  const int w = tid >> 6, lane = tid & 63;
  const int wr = w >> 1, wc = w & 1;
  const int l15 = lane & 15, l4 = lane >> 4;

  f32x4 acc[4][4];
#pragma unroll
  for (int m = 0; m < 4; m++)
#pragma unroll
    for (int n = 0; n < 4; n++) acc[m][n] = (f32x4){0.f, 0.f, 0.f, 0.f};

  const int rr = lane >> 3;        // 8 rows per 1KB wave-instr (128B rows)
  const int c8 = (lane & 7) * 8;   // 8 chunks of 8 bf16 per 128B row

  for (int k0 = 0; k0 < K; k0 += 64) {
    const bf16* gA = A + (size_t)(row0 + w * 32 + rr) * K + k0 + c8;
    const bf16* gB = BT + (size_t)(col0 + w * 32 + rr) * K + k0 + c8;
#pragma unroll
    for (int i = 0; i < 4; i++) {
      stage16(gA + (size_t)(8 * i) * K, As + (w * 32 + 8 * i) * 64);
      stage16(gB + (size_t)(8 * i) * K, Bs + (w * 32 + 8 * i) * 64);
    }
    __syncthreads();

#pragma unroll
    for (int hh = 0; hh < 2; hh++) {
      bf16x8 af[4], bfv[4];
#pragma unroll
      for (int m = 0; m < 4; m++)
        af[m] = *reinterpret_cast<const bf16x8*>(
            As + (wr * 64 + m * 16 + l15) * 64 + hh * 32 + l4 * 8);
#pragma unroll
      for (int n = 0; n < 4; n++)
        bfv[n] = *reinterpret_cast<const bf16x8*>(
            Bs + (wc * 64 + n * 16 + l15) * 64 + hh * 32 + l4 * 8);
#pragma unroll
      for (int m = 0; m < 4; m++)
#pragma unroll
        for (int n = 0; n < 4; n++)
          acc[m][n] = __builtin_amdgcn_mfma_f32_16x16x32_bf16(af[m], bfv[n], acc[m][n], 0, 0, 0);
    }
    __syncthreads();
  }

  const int orow = row0 + wr * 64;
  const int ocol = col0 + wc * 64;
#pragma unroll
  for (int m = 0; m < 4; m++) {
#pragma unroll
    for (int n = 0; n < 4; n++) {
      const int c = ocol + n * 16 + l15;
#pragma unroll
      for (int j = 0; j < 4; j++) {
        const int r = orow + m * 16 + l4 * 4 + j;  // C/D: col=lane&15, row=(lane>>4)*4+reg
        const size_t idx = (size_t)r * N + c;
        const float v = acc[m][n][j];
        if (EPI == 0) {
          ((bf16*)Cout)[idx] = (bf16)v;
        } else if (EPI == 1) {
          ((float*)Cout)[idx] = res[idx] + v;
        } else if (EPI == 2) {
          const float h = v + bias[c];
          ((bf16*)Cout)[idx] = (bf16)(0.5f * h * (1.0f + erff(h * 0.70710678118f)));
        } else {
          ((float*)Cout)[idx] = res[idx] + v;
        }
      }
    }
  }
}

// ------------------------------------------------------------------ attention
// kqv [T][2304] bf16 : k at +0, q at +768, v at +1536, head offset h*64
// Writes UNNORMALIZED partials:  Opart[half][4096][768] f32,
//                                Lpart[half][12][4096]  f32.
// grid (32 qb, 12 h, 2 kv-half); no-max softmax (P = exp2(st), |st| << 127)
// makes partials EXACTLY additive: O = sum(accO) / sum(accL).
//
// 32x32x16 MFMA version: wave owns 32 q (q = lane&31); LDS fragment reads
// per FLOP HALVE vs 16x16x32 (16B feeds 32K FLOP) -- the kernel was LDS-BW
// bound (R5/R8 analysis). Block = 4 waves x 32 q (QB=128); KV tile = 128.
//
// Swapped QK^T: S^T = mfma32(A=K, B=Q); C-layout col=lane&31=q,
// row = (reg&3) + 8*(reg>>2) + 4*hi  (hi = lane>>5), so lane holds P for 16
// of 32 positions (its hi half). Key-relabel: position p (tile t = p>>5,
// r4 = p&3, hi_p = (p>>2)&1, s4 = (p>>3)&3) gets label
//   L(p) = 32t + 16*(s4>>1) + 8*hi_p + (r4 + 4*(s4&1))      [bijective]
// so PV B-frag (col=q, k=(lane>>5)*8+e per 16-key chunk) is exactly the
// lane's own registers: pb[2t + (reg>>3)][(reg&3) + 4*((reg>>2)&1)].
// V scattered to Vt[d][L] at staging. L-row-sum: 64 in-reg adds + one final
// shfl_xor(32). Bank conflicts: odd-16B row strides (K 144B, Vt 272B), no XOR.
// K/V reg-staged with cross-iteration prefetch.
__global__ __launch_bounds__(256, 3)
void attn_fused(const bf16* __restrict__ kqv,
                float* __restrict__ Opart,
                float* __restrict__ Lpart) {
  const int qb = blockIdx.x, h = blockIdx.y, half = blockIdx.z;
  const int tid = threadIdx.x, w = tid >> 6, lane = tid & 63;
  const int l31 = lane & 31, hi = lane >> 5;

  __shared__ __align__(16) char KsB[128 * 144];  // K [pos][64d], stride 144B
  __shared__ __align__(16) char VtB[64 * 272];   // V^T [d][128 labels], 272B

  // Q fragments (B operand): col=q=l31, k = hi*8 + e (+16 per frag)
  const int qrow = qb * 128 + w * 32 + l31;
  const bf16* qp = kqv + (size_t)qrow * 2304 + 768 + h * 64;
  bf16x8 qf[4];
#pragma unroll
  for (int m = 0; m < 4; m++)
    qf[m] = *reinterpret_cast<const bf16x8*>(qp + hi * 8 + 16 * m);
  const float cscale = 0.125f * 1.4426950408889634f;
#pragma unroll
  for (int m = 0; m < 4; m++)
#pragma unroll
    for (int e = 0; e < 8; e++) qf[m][e] = (bf16)((float)qf[m][e] * cscale);

  f32x16 accO0 = zero16(), accO1 = zero16();
  float lsum = 0.f;

  // K staging: row = tid>>1 (0..127), 64B half = tid&1 (4 b128 chunks)
  const int krow = tid >> 1;
  const int kc0 = (tid & 1) * 4;
  // V staging: keys kb*4..+3, d = db*8..+7; label base (bijective in kb):
  const int kb = tid & 31, db = tid >> 5;
  const int lb = ((kb >> 3) & 3) * 32 + ((kb >> 2) & 1) * 16 + (kb & 1) * 8 +
                 ((kb >> 1) & 1) * 4;

  const int kt0 = half * 16;  // this block's 16 key-tiles

  bf16x8 kreg[4], vreg[4];
#define LOADKV(kt)                                                               \
  {                                                                              \
    const bf16* kp =                                                             \
        kqv + (size_t)((kt)*128 + krow) * 2304 + h * 64 + kc0 * 8;               \
    _Pragma("unroll") for (int i = 0; i < 4; i++)                                \
        kreg[i] = *reinterpret_cast<const bf16x8*>(kp + i * 8);                  \
    const bf16* vp =                                                             \
        kqv + (size_t)((kt)*128 + kb * 4) * 2304 + 1536 + h * 64 + db * 8;       \
    _Pragma("unroll") for (int r = 0; r < 4; r++)                                \
        vreg[r] = *reinterpret_cast<const bf16x8*>(vp + (size_t)r * 2304);       \
  }

  LOADKV(kt0);

  for (int kt = 0; kt < 16; kt++) {
    __syncthreads();
    // ---- LDS writes from registers
    {
      char* kdst = KsB + krow * 144;
#pragma unroll
      for (int i = 0; i < 4; i++)
        *reinterpret_cast<bf16x8*>(kdst + (kc0 + i) * 16) = kreg[i];
#pragma unroll
      for (int e = 0; e < 8; e++) {
        const int d = db * 8 + e;
        const bf16x4 pk4 = (bf16x4){vreg[0][e], vreg[1][e], vreg[2][e], vreg[3][e]};
        *reinterpret_cast<bf16x4*>(VtB + d * 272 + lb * 2) = pk4;
      }
    }
    __syncthreads();
    if (kt + 1 < 16) LOADKV(kt0 + kt + 1);  // prefetch flies during compute

    // ---- QK^T (4 pos-tiles of 32) -> exp2 -> pack lane-local PV B-frags
    bf16x8 pb[8];
#pragma unroll
    for (int t = 0; t < 4; t++) {
      f32x16 st = zero16();
#pragma unroll
      for (int m = 0; m < 4; m++) {
        const bf16x8 kf = *reinterpret_cast<const bf16x8*>(
            KsB + (size_t)(32 * t + l31) * 144 + (2 * m + hi) * 16);
        st = __builtin_amdgcn_mfma_f32_32x32x16_bf16(kf, qf[m], st, 0, 0, 0);
      }
#pragma unroll
      for (int reg = 0; reg < 16; reg++) {
        const float pv = exp2f(st[reg]);
        lsum += pv;
        pb[2 * t + (reg >> 3)][(reg & 3) + 4 * ((reg >> 2) & 1)] = (bf16)pv;
      }
    }

    // ---- O^T += V^T @ P^T : 2 d-tiles x 8 key-chunks of 16
#pragma unroll
    for (int mk = 0; mk < 8; mk++) {
      const bf16x8 vf0 = *reinterpret_cast<const bf16x8*>(
          VtB + (size_t)l31 * 272 + (2 * mk + hi) * 16);
      accO0 = __builtin_amdgcn_mfma_f32_32x32x16_bf16(vf0, pb[mk], accO0, 0, 0, 0);
      const bf16x8 vf1 = *reinterpret_cast<const bf16x8*>(
          VtB + (size_t)(32 + l31) * 272 + (2 * mk + hi) * 16);
      accO1 = __builtin_amdgcn_mfma_f32_32x32x16_bf16(vf1, pb[mk], accO1, 0, 0, 0);
    }
  }
#undef LOADKV

  // ---- epilogue: write unnormalized partials (f32)
  // accO row d = 32*dt + (reg&3) + 8*(reg>>2) + 4*hi, col q = l31
  lsum += __shfl_xor(lsum, 32);
  float* Oq = Opart + (size_t)half * T_SEQ * C_EMB + (size_t)qrow * C_EMB + h * 64;
#pragma unroll
  for (int s4 = 0; s4 < 4; s4++) {
    const f32x4 o0 = (f32x4){accO0[4 * s4 + 0], accO0[4 * s4 + 1],
                             accO0[4 * s4 + 2], accO0[4 * s4 + 3]};
    *reinterpret_cast<f32x4*>(Oq + 8 * s4 + 4 * hi) = o0;
    const f32x4 o1 = (f32x4){accO1[4 * s4 + 0], accO1[4 * s4 + 1],
                             accO1[4 * s4 + 2], accO1[4 * s4 + 3]};
    *reinterpret_cast<f32x4*>(Oq + 32 + 8 * s4 + 4 * hi) = o1;
  }
  if (hi == 0)
    Lpart[(size_t)half * NHEAD * T_SEQ + (size_t)h * T_SEQ + qrow] = lsum;
}

// ------------------------------------------------------- attention combine
// out[q][c] = (O0[q][c] + O1[q][c]) / (L0[h][q] + L1[h][q]),  h = c/64
__global__ void attn_combine(const float* __restrict__ Opart,
                             const float* __restrict__ Lpart,
                             bf16* __restrict__ out) {
  const int q = blockIdx.x, t = threadIdx.x;  // 256 threads
  const float* O0 = Opart + (size_t)q * C_EMB;
  const float* O1 = O0 + (size_t)T_SEQ * C_EMB;
#pragma unroll
  for (int i = 0; i < 3; i++) {
    const int c = t + i * 256;
    const int h = c >> 6;
    const float L = Lpart[(size_t)h * T_SEQ + q] +
                    Lpart[(size_t)NHEAD * T_SEQ + (size_t)h * T_SEQ + q];
    out[(size_t)q * C_EMB + c] = (bf16)((O0[c] + O1[c]) / L);
  }
}

// ------------------------------------------------------------------ launch
extern "C" void kernel_launch(void* const* d_in, const int* in_sizes, int n_in,
                              void* d_out, int out_size, void* d_ws, size_t ws_size,
                              hipStream_t stream) {
  const float* x       = (const float*)d_in[0];
  const float* W_kqv   = (const float*)d_in[1];
  const float* W_proj  = (const float*)d_in[2];
  const float* W_fc    = (const float*)d_in[3];
  const float* b_fc    = (const float*)d_in[4];
  const float* W_cproj = (const float*)d_in[5];
  float* outp = (float*)d_out;

  char* p = (char*)d_ws;
  bf16* Wkqv_t  = (bf16*)p; p += (size_t)2304 * 768 * 2;
  bf16* Wproj_t = (bf16*)p; p += (size_t)768 * 768 * 2;
  bf16* Wfc_t   = (bf16*)p; p += (size_t)1536 * 768 * 2;
  bf16* Wcp_t   = (bf16*)p; p += (size_t)768 * 1536 * 2;
  bf16* A1      = (bf16*)p; p += (size_t)4096 * 768 * 2;   // aliased: attn_out
  bf16* KQV     = (bf16*)p; p += (size_t)4096 * 2304 * 2;  // aliased: A2 | Hg
  float* x1     = (float*)p; p += (size_t)4096 * 768 * 4;
  // attn partials: half 0 aliases x1 (x1 is written AFTER combine consumed
  // the partials, by the proj GEMM); half 1 + Lpart are fresh ws.
  float* Opart  = x1;       p += (size_t)4096 * 768 * 4;   // half 1
  float* Lpart  = (float*)p; p += (size_t)2 * NHEAD * 4096 * 4;
  bf16* attn_o = A1;
  bf16* A2     = KQV;
  bf16* Hg     = KQV + (size_t)4096 * 768;

  // weights: f32 [K][N] -> bf16 [N][K]
  wt_transpose<<<dim3(2304 / 32, 768 / 32), 256, 0, stream>>>(W_kqv, Wkqv_t, 768, 2304);
  wt_transpose<<<dim3(768 / 32, 768 / 32), 256, 0, stream>>>(W_proj, Wproj_t, 768, 768);
  wt_transpose<<<dim3(1536 / 32, 768 / 32), 256, 0, stream>>>(W_fc, Wfc_t, 768, 1536);
  wt_transpose<<<dim3(768 / 32, 1536 / 32), 256, 0, stream>>>(W_cproj, Wcp_t, 1536, 768);

  ln_rows<<<4096, 256, 0, stream>>>(x, A1);
  gemm_bt<0><<<dim3(32, 18), 256, 0, stream>>>(A1, Wkqv_t, KQV, nullptr, nullptr,
                                               4096, 2304, 768);
  attn_fused<<<dim3(32, 12, 2), 256, 0, stream>>>(KQV, Opart, Lpart);
  attn_combine<<<4096, 256, 0, stream>>>(Opart, Lpart, attn_o);
  gemm_bt<1><<<dim3(32, 6), 256, 0, stream>>>(attn_o, Wproj_t, x1, x, nullptr,
                                              4096, 768, 768);
  ln_rows<<<4096, 256, 0, stream>>>(x1, A2);
  gemm_bt<2><<<dim3(32, 12), 256, 0, stream>>>(A2, Wfc_t, Hg, nullptr, b_fc,
                                               4096, 1536, 768);
  gemm_bt<3><<<dim3(32, 6), 256, 0, stream>>>(Hg, Wcp_t, outp, x1, nullptr,
                                              4096, 768, 1536);
}